// Round 7
// baseline (468.267 us; speedup 1.0000x reference)
//
#include <hip/hip_runtime.h>

// Decoder_33208687133135 — fused Koopman decoder, MI355X (gfx950).
// Only the diagonal of s,t survives -> layer4 is a per-row dot with one W4
// column. ~292 GFLOP, f16 MFMA (absmax 0.03125 vs thr 0.2425).
//
// R10 post-mortem: A-dbuf+B-depth-2 spilled (WRITE 78MB) and dur was
// IDENTICAL (378) to R9-clean and R8-conflicted. Time invariant to
// scheduling, conflicts, and spill -> none are critical. Model: both
// co-resident blocks run the same barrier cadence in lockstep; per-CU time
// = MFMA/read phase (~140us) + EXPOSED tanh+scatter-write phase. The 64x
// ds_write_b16/thread-layer come from the C/D(col-slice) vs A-frag(row-run)
// mismatch.
// R11: TRANSPOSED FLOW. Compute H^T = W^T * Hprev^T: A-operand = W^T frags
// (elementwise identical to existing wpack!), B-operand = activations in
// B-frag layout. C/D rows are then next-layer k' and regs rq*4+{0..3} are 4
// consecutive k' -> 16x ds_write_b64 (4x fewer DS write instrs, bank-clean:
// verified full 32-bank coverage, data-bound). Layer-1 B-operand = koop[b]
// UNtransposed (staging transpose deleted); bias folded into tanh phase as
// coalesced float4; tanh+pack pre-barrier; swizzle machinery deleted;
// depth-1 prefetch only (~110 regs, no spill).
// Tripwires: WRITE ~0.5MB, FETCH ~26MB, conflicts <2e6. If dur stays ~378
// clean -> lockstep phase serialization; next = net-per-block + ws combine.

typedef _Float16 f16;
typedef _Float16 f16x4 __attribute__((ext_vector_type(4)));
typedef _Float16 f16x8 __attribute__((ext_vector_type(8)));
typedef float f32x16 __attribute__((ext_vector_type(16)));

#define WPACK_PER_NET 589824
#define OFF_W1 0
#define OFF_W2 32768
#define OFF_W3 294912
#define OFF_W4T 557056
#define WPACK_BYTES (2u * WPACK_PER_NET * sizeof(f16))  // 2.36 MB

// ---------------- prologue: pack weights fp32 -> f16 blocked -------------
// Stored block (ks,g): value W[ks*16 + 8*(lane>>5) + j][g*32 + (lane&31)].
// Read as A-fragment of W^T (A[m][k]=W[k][m], m=lane&31, k=8*(lane>>5)+j)
// — elementwise identical to the old B-frag-of-W pack, so unchanged.
__global__ void pack_weights(const float* __restrict__ sW1, const float* __restrict__ sW2,
                             const float* __restrict__ sW3, const float* __restrict__ sW4,
                             const float* __restrict__ tW1, const float* __restrict__ tW2,
                             const float* __restrict__ tW3, const float* __restrict__ tW4,
                             f16* __restrict__ dst) {
  int idx8 = (blockIdx.x * 256 + threadIdx.x) * 8;
  if (idx8 >= 2 * WPACK_PER_NET) return;
  int net = idx8 >= WPACK_PER_NET;
  int f = idx8 - net * WPACK_PER_NET;
  const float* W1 = net ? tW1 : sW1;
  const float* W2 = net ? tW2 : sW2;
  const float* W3 = net ? tW3 : sW3;
  const float* W4 = net ? tW4 : sW4;
  f16x8 o;
  if (f < OFF_W2) {               // W1: (64,512), ks<4
    int lane = (f >> 3) & 63, g = (f >> 9) & 15, ks = f >> 13;
    int r0 = ks * 16 + (lane >> 5) * 8, c = g * 32 + (lane & 31);
#pragma unroll
    for (int j = 0; j < 8; j++) o[j] = (f16)W1[(r0 + j) * 512 + c];
  } else if (f < OFF_W3) {        // W2: (512,512), ks<32
    int f2 = f - OFF_W2;
    int lane = (f2 >> 3) & 63, g = (f2 >> 9) & 15, ks = f2 >> 13;
    int r0 = ks * 16 + (lane >> 5) * 8, c = g * 32 + (lane & 31);
#pragma unroll
    for (int j = 0; j < 8; j++) o[j] = (f16)W2[(r0 + j) * 512 + c];
  } else if (f < OFF_W4T) {       // W3: (512,512)
    int f3 = f - OFF_W3;
    int lane = (f3 >> 3) & 63, g = (f3 >> 9) & 15, ks = f3 >> 13;
    int r0 = ks * 16 + (lane >> 5) * 8, c = g * 32 + (lane & 31);
#pragma unroll
    for (int j = 0; j < 8; j++) o[j] = (f16)W3[(r0 + j) * 512 + c];
  } else {                        // W4T (kept for layout stability; epilogue
    int f4 = f - OFF_W4T;         //  reads raw fp32 W4 instead)
    int i = f4 >> 9, k0 = f4 & 511;
#pragma unroll
    for (int j = 0; j < 8; j++) o[j] = (f16)W4[(k0 + j) * 64 + i];
  }
  *(f16x8*)(dst + net * WPACK_PER_NET + f) = o;
}

// B-fragment flat index for the activation tile T[k][j] (k = reduction,
// j = batch-row d in [0,64)): frag (ks = k>>4, jt = j>>5), lane =
// (j&31) + 32*((k>>3)&1), elem = k&7.
__device__ __forceinline__ int zbidx(int k, int j) {
  return ((k >> 4) * 2 + (j >> 5)) * 512 + ((j & 31) + 32 * ((k >> 3) & 1)) * 8 + (k & 7);
}

// tanh(x) = 1 - 2/(exp(2x)+1). Saturates correctly at +/-inf.
__device__ __forceinline__ float fast_tanh(float x) {
  float e = __expf(x + x);
  return fmaf(-2.0f, __builtin_amdgcn_rcpf(e + 1.0f), 1.0f);
}

// Load the wave's 2 A-fragments (W^T, output rows i in [64w,64w+64)) for
// k-slice ks. PACKED: 16B lane-contiguous loads from wpack (L2).
// DIRECT: strided fp32 gather from row-major W, convert in regs.
template <bool PACKED>
__device__ __forceinline__ void load_a(const f16* __restrict__ Wblk,
                                       const float* __restrict__ Wraw,
                                       int ks, int wave, int lane, f16x8* adst) {
  if (PACKED) {
#pragma unroll
    for (int it = 0; it < 2; it++)
      adst[it] = *(const f16x8*)(Wblk + ((ks * 16 + wave * 2 + it) * 64 + lane) * 8);
  } else {
    int r0 = ks * 16 + (lane >> 5) * 8;
    int n0 = wave * 64 + (lane & 31);
#pragma unroll
    for (int it = 0; it < 2; it++) {
      f16x8 v;
#pragma unroll
      for (int j = 0; j < 8; j++) v[j] = (f16)Wraw[(r0 + j) * 512 + n0 + it * 32];
      adst[it] = v;
    }
  }
}

// One MLP layer, transposed: Tout = tanh(W^T(512xK) . Tin(Kx64) + b),
// both tiles in B-frag layout. 8 waves; wave w owns output rows (= next
// layer's k') [64w,64w+64) via 2x2 32x32 MFMA tiles (it = i-tile,
// jt = batch-col tile). Weights stream L2->VGPR depth-1; B-frags from LDS
// (2 ds_read_b128 per ks feed 4 MFMAs).
// C/D (m74/m101): col = j = jt*32+(lane&31); row-local = (reg&3) + 8*(reg>>2)
// + 4*(lane>>5), reg = rq*4+rr -> k' = wave*64+it*32+rr+8rq+4h: rr=0..3 are
// 4 CONSECUTIVE k' -> one f16x4 (ds_write_b64) per (it,jt,rq).
// Write elem = wbase + it*2048 + jt*512 + (rq>>1)*1024 + (rq&1)*256, with
// wbase = wave*4096 + (lane&31)*8 + 4*(lane>>5).
// [verified (w,l,it,jt,rq,rr)=(0,37,1,1,3,2): k'=62,j=37 -> elem 3886 ✓]
template <int NS, bool PACKED, bool ALIASED>
__device__ __forceinline__ void mlp_layer(const f16* __restrict__ Wblk,
                                          const float* __restrict__ Wraw,
                                          const float* __restrict__ bias,
                                          const f16* Bsrc, f16* Tout,
                                          int wave, int lane) {
  f32x16 acc[2][2];
#pragma unroll
  for (int it = 0; it < 2; it++)
#pragma unroll
    for (int jt = 0; jt < 2; jt++)
#pragma unroll
      for (int e = 0; e < 16; e++) acc[it][jt][e] = 0.f;

  f16x8 aw[2][2];  // depth-1 alternating weight prefetch
  load_a<PACKED>(Wblk, Wraw, 0, wave, lane, aw[0]);
#pragma unroll
  for (int ks = 0; ks < NS; ks++) {
    if (ks + 1 < NS) load_a<PACKED>(Wblk, Wraw, ks + 1, wave, lane, aw[(ks + 1) & 1]);
    const f16* bb = Bsrc + ks * 1024 + lane * 8;
    f16x8 b0 = *(const f16x8*)bb;          // jt=0
    f16x8 b1 = *(const f16x8*)(bb + 512);  // jt=1
#pragma unroll
    for (int it = 0; it < 2; it++) {
      acc[it][0] = __builtin_amdgcn_mfma_f32_32x32x16_f16(aw[ks & 1][it], b0,
                                                          acc[it][0], 0, 0, 0);
      acc[it][1] = __builtin_amdgcn_mfma_f32_32x32x16_f16(aw[ks & 1][it], b1,
                                                          acc[it][1], 0, 0, 0);
    }
  }

  // Bias + tanh + f16 pack BEFORE the barrier (pure reg/VALU work).
  // bias index: i = wave*64 + it*32 + 8*rq + 4*h + rr, rr=0..3 -> float4.
  const int h = lane >> 5;
  f16x4 hv[2][2][4];
#pragma unroll
  for (int it = 0; it < 2; it++)
#pragma unroll
    for (int rq = 0; rq < 4; rq++) {
      float4 bv = *(const float4*)&bias[wave * 64 + it * 32 + rq * 8 + h * 4];
#pragma unroll
      for (int jt = 0; jt < 2; jt++) {
        f16x4 v;
#pragma unroll
        for (int rr = 0; rr < 4; rr++)
          v[rr] = (f16)fast_tanh(acc[it][jt][rq * 4 + rr] + (&bv.x)[rr]);
        hv[it][jt][rq] = v;
      }
    }

  if (ALIASED) __syncthreads();  // all waves done reading Bsrc (== Tout)

  f16* wb = Tout + wave * 4096 + (lane & 31) * 8 + 4 * h;
#pragma unroll
  for (int it = 0; it < 2; it++)
#pragma unroll
    for (int jt = 0; jt < 2; jt++)
#pragma unroll
      for (int rq = 0; rq < 4; rq++)
        *(f16x4*)(wb + it * 2048 + jt * 512 + (rq >> 1) * 1024 + (rq & 1) * 256) =
            hv[it][jt][rq];
  __syncthreads();
}

template <bool PACKED>
__global__ __launch_bounds__(512, 4) void decoder_main(
    const float* __restrict__ x, const float* __restrict__ koop,
    const f16* __restrict__ wpack,
    const float* __restrict__ sW1, const float* __restrict__ sW2,
    const float* __restrict__ sW3, const float* __restrict__ sW4,
    const float* __restrict__ tW1, const float* __restrict__ tW2,
    const float* __restrict__ tW3, const float* __restrict__ tW4,
    const float* __restrict__ sb1, const float* __restrict__ sb2,
    const float* __restrict__ sb3, const float* __restrict__ sb4,
    const float* __restrict__ tb1, const float* __restrict__ tb2,
    const float* __restrict__ tb3, const float* __restrict__ tb4,
    float* __restrict__ out) {
  __shared__ __align__(16) f16 ZB[4096];   // koop tile, B-frag order (8 KB)
  __shared__ __align__(16) f16 HA[32768];  // activations T[k][j] (64 KB)
  __shared__ float pp[512];                // epilogue partials 8x64 (2 KB)
  __shared__ float redBuf[2][64];          // ds, dt
  // ~74.6 KB; 512 thr, ~110 regs -> 2 blocks/CU (16 waves, 4/SIMD)

  const int b = blockIdx.x;
  const int t = threadIdx.x;
  const int wave = t >> 6, lane = t & 63;

  // Stage layer-1 B-operand: B[k][j] = z^T[k][j] = koop[b][k][j] — the raw
  // koop row-major tile, NO transpose. Coalesced fp32 reads.
  const float* kb = koop + b * 4096;
#pragma unroll
  for (int i = 0; i < 8; i++) {
    int flat = t + 512 * i;                 // k = flat>>6, j = flat&63
    ZB[zbidx(flat >> 6, flat & 63)] = (f16)kb[flat];
  }
  __syncthreads();

  for (int net = 0; net < 2; net++) {
    const f16* wb = PACKED ? (wpack + net * WPACK_PER_NET) : (const f16*)0;
    const float* W1 = net ? tW1 : sW1;
    const float* W2 = net ? tW2 : sW2;
    const float* W3 = net ? tW3 : sW3;
    const float* W4 = net ? tW4 : sW4;
    const float* b1 = net ? tb1 : sb1;
    const float* b2 = net ? tb2 : sb2;
    const float* b3 = net ? tb3 : sb3;
    const float* b4 = net ? tb4 : sb4;
    // L1 reads ZB (never overwritten), writes HA -> no pre-write barrier.
    mlp_layer<4, PACKED, false>(PACKED ? wb + OFF_W1 : 0, W1, b1, ZB, HA, wave, lane);
    mlp_layer<32, PACKED, true>(PACKED ? wb + OFF_W2 : 0, W2, b2, HA, HA, wave, lane);
    mlp_layer<32, PACKED, true>(PACKED ? wb + OFF_W3 : 0, W3, b3, HA, HA, wave, lane);

    // Diagonal epilogue: ds[d] = H3[d,:] . W4[:,d] + b4[d].
    // H3[d][k] = T[k][d]; lane = d, wave covers k in [64w,64w+64).
    // Reads: f16x8 at zbidx(k0, lane) — contiguous 8 elems, lanes hit
    // consecutive 16B slots (conflict-free). W4 raw fp32, coalesced over d.
    {
      float p = 0.f;
#pragma unroll
      for (int q = 0; q < 8; q++) {
        int k0 = wave * 64 + q * 8;
        f16x8 hv = *(const f16x8*)&HA[zbidx(k0, lane)];
#pragma unroll
        for (int j = 0; j < 8; j++)
          p += (float)hv[j] * W4[(k0 + j) * 64 + lane];
      }
      pp[wave * 64 + lane] = p;
    }
    __syncthreads();
    if (t < 64) {
      float s = b4[t];
#pragma unroll
      for (int o = 0; o < 8; o++) s += pp[o * 64 + t];
      redBuf[net][t] = s;
    }
    __syncthreads();  // pp/HA reusable; redBuf[net] visible at the end
  }

  if (t < 64) {
    out[b * 64 + t] = (x[b * 64 + t] - redBuf[1][t]) * __expf(-redBuf[0][t]);
  }
}

extern "C" void kernel_launch(void* const* d_in, const int* in_sizes, int n_in,
                              void* d_out, int out_size, void* d_ws, size_t ws_size,
                              hipStream_t stream) {
  const float* x    = (const float*)d_in[0];
  const float* koop = (const float*)d_in[1];
  const float* sW1 = (const float*)d_in[2];  const float* sb1 = (const float*)d_in[3];
  const float* sW2 = (const float*)d_in[4];  const float* sb2 = (const float*)d_in[5];
  const float* sW3 = (const float*)d_in[6];  const float* sb3 = (const float*)d_in[7];
  const float* sW4 = (const float*)d_in[8];  const float* sb4 = (const float*)d_in[9];
  const float* tW1 = (const float*)d_in[10]; const float* tb1 = (const float*)d_in[11];
  const float* tW2 = (const float*)d_in[12]; const float* tb2 = (const float*)d_in[13];
  const float* tW3 = (const float*)d_in[14]; const float* tb3 = (const float*)d_in[15];
  const float* tW4 = (const float*)d_in[16]; const float* tb4 = (const float*)d_in[17];
  float* out = (float*)d_out;

  // Launch-invariant branch (ws_size constant across calls) -> graph-safe.
  // NEVER write past ws_size (R1: OOB pack corrupted harness allocations).
  if (ws_size >= (size_t)WPACK_BYTES) {
    f16* wpack = (f16*)d_ws;
    pack_weights<<<576, 256, 0, stream>>>(sW1, sW2, sW3, sW4, tW1, tW2, tW3, tW4, wpack);
    decoder_main<true><<<2048, 512, 0, stream>>>(
        x, koop, wpack, sW1, sW2, sW3, sW4, tW1, tW2, tW3, tW4,
        sb1, sb2, sb3, sb4, tb1, tb2, tb3, tb4, out);
  } else {
    decoder_main<false><<<2048, 512, 0, stream>>>(
        x, koop, (const f16*)0, sW1, sW2, sW3, sW4, tW1, tW2, tW3, tW4,
        sb1, sb2, sb3, sb4, tb1, tb2, tb3, tb4, out);
  }
}

// Round 8
// 454.296 us; speedup vs baseline: 1.0308x; 1.0308x over previous
//
#include <hip/hip_runtime.h>

// Decoder_33208687133135 — fused Koopman decoder, MI355X (gfx950).
// Only the diagonal of s,t survives -> layer4 is a per-row dot with one W4
// column. ~292 GFLOP, f16 MFMA (absmax 0.03125 vs thr 0.2425).
//
// R11 post-mortem: clean (VGPR 60, WRITE 0.5MB, conflicts 7e6), 390us.
// Eight variants (R4-R11) land 350-390 invariant to shape/conflicts/spill/
// schedule/layout: time is set by exposed inter-layer phases + per-iter
// dependent latency, no pipe saturated (MFMA 36, DS 26, VMEM 9, VALU 5%).
// R12: (1) FUSE the diagonal epilogue into L3's registers — after the
// transposed L3, each lane holds acc3 for known (k', d): tanh + fmaf vs
// coalesced raw-fp32 W4 + one shfl_down(32) + 2 pp floats. Deletes the H3
// write phase, the epilogue LDS-read phase, and 2 barriers per net (7->5).
// (2) Explicit B-LDS prefetch 1 ks ahead, fully-unrolled loop (static
// indices; ~110 regs: acc 64 + aw 16 + bn 16 + misc). (3) setprio around
// MFMA. Pack kernel skips the unused W4T region.
// Tripwires: WRITE ~0.5MB, VGPR <=128 no spill, conflicts <=7e6.
// Pre-commit: >=375 clean -> structural plateau; stop scheduling work.

typedef _Float16 f16;
typedef _Float16 f16x4 __attribute__((ext_vector_type(4)));
typedef _Float16 f16x8 __attribute__((ext_vector_type(8)));
typedef float f32x16 __attribute__((ext_vector_type(16)));

#define WPACK_PER_NET 589824
#define OFF_W1 0
#define OFF_W2 32768
#define OFF_W3 294912
#define PACK_ELEMS 557056  // W1+W2+W3 only (W4 consumed raw by epilogue)
#define WPACK_BYTES (2u * WPACK_PER_NET * sizeof(f16))  // 2.36 MB

// ---------------- prologue: pack weights fp32 -> f16 blocked -------------
// Stored block (ks,g): value W[ks*16 + 8*(lane>>5) + j][g*32 + (lane&31)].
// Read as A-fragment of W^T (A[m][k]=W[k][m], m=lane&31, k=8*(lane>>5)+j).
__global__ void pack_weights(const float* __restrict__ sW1, const float* __restrict__ sW2,
                             const float* __restrict__ sW3,
                             const float* __restrict__ tW1, const float* __restrict__ tW2,
                             const float* __restrict__ tW3,
                             f16* __restrict__ dst) {
  int idx8 = (blockIdx.x * 256 + threadIdx.x) * 8;
  if (idx8 >= 2 * PACK_ELEMS) return;
  int net = idx8 >= PACK_ELEMS;
  int f = idx8 - net * PACK_ELEMS;
  const float* W1 = net ? tW1 : sW1;
  const float* W2 = net ? tW2 : sW2;
  const float* W3 = net ? tW3 : sW3;
  f16x8 o;
  if (f < OFF_W2) {               // W1: (64,512), ks<4
    int lane = (f >> 3) & 63, g = (f >> 9) & 15, ks = f >> 13;
    int r0 = ks * 16 + (lane >> 5) * 8, c = g * 32 + (lane & 31);
#pragma unroll
    for (int j = 0; j < 8; j++) o[j] = (f16)W1[(r0 + j) * 512 + c];
  } else if (f < OFF_W3) {        // W2: (512,512), ks<32
    int f2 = f - OFF_W2;
    int lane = (f2 >> 3) & 63, g = (f2 >> 9) & 15, ks = f2 >> 13;
    int r0 = ks * 16 + (lane >> 5) * 8, c = g * 32 + (lane & 31);
#pragma unroll
    for (int j = 0; j < 8; j++) o[j] = (f16)W2[(r0 + j) * 512 + c];
  } else {                        // W3: (512,512)
    int f3 = f - OFF_W3;
    int lane = (f3 >> 3) & 63, g = (f3 >> 9) & 15, ks = f3 >> 13;
    int r0 = ks * 16 + (lane >> 5) * 8, c = g * 32 + (lane & 31);
#pragma unroll
    for (int j = 0; j < 8; j++) o[j] = (f16)W3[(r0 + j) * 512 + c];
  }
  *(f16x8*)(dst + net * WPACK_PER_NET + f) = o;
}

// B-fragment flat index for the activation tile T[k][j] (k = reduction,
// j = batch-row d in [0,64)): frag (ks = k>>4, jt = j>>5), lane =
// (j&31) + 32*((k>>3)&1), elem = k&7.
__device__ __forceinline__ int zbidx(int k, int j) {
  return ((k >> 4) * 2 + (j >> 5)) * 512 + ((j & 31) + 32 * ((k >> 3) & 1)) * 8 + (k & 7);
}

// tanh(x) = 1 - 2/(exp(2x)+1). Saturates correctly at +/-inf.
__device__ __forceinline__ float fast_tanh(float x) {
  float e = __expf(x + x);
  return fmaf(-2.0f, __builtin_amdgcn_rcpf(e + 1.0f), 1.0f);
}

// Load the wave's 2 A-fragments (W^T, output rows i in [64w,64w+64)) for
// k-slice ks. PACKED: 16B lane-contiguous loads from wpack (L2).
// DIRECT: strided fp32 gather from row-major W, convert in regs.
template <bool PACKED>
__device__ __forceinline__ void load_a(const f16* __restrict__ Wblk,
                                       const float* __restrict__ Wraw,
                                       int ks, int wave, int lane, f16x8* adst) {
  if (PACKED) {
#pragma unroll
    for (int it = 0; it < 2; it++)
      adst[it] = *(const f16x8*)(Wblk + ((ks * 16 + wave * 2 + it) * 64 + lane) * 8);
  } else {
    int r0 = ks * 16 + (lane >> 5) * 8;
    int n0 = wave * 64 + (lane & 31);
#pragma unroll
    for (int it = 0; it < 2; it++) {
      f16x8 v;
#pragma unroll
      for (int j = 0; j < 8; j++) v[j] = (f16)Wraw[(r0 + j) * 512 + n0 + it * 32];
      adst[it] = v;
    }
  }
}

// Shared MFMA K-loop: acc[it][jt] += W^T-frag(ks,it) x Bsrc-frag(ks,jt).
// Fully unrolled (static parity indices); A (global) and B (LDS) both
// prefetched one ks ahead; setprio(1) around the MFMA cluster.
template <int NS, bool PACKED>
__device__ __forceinline__ void kloop(const f16* __restrict__ Wblk,
                                      const float* __restrict__ Wraw,
                                      const f16* Bsrc, int wave, int lane,
                                      f32x16 acc[2][2]) {
  f16x8 aw[2][2], bn[2][2];
  load_a<PACKED>(Wblk, Wraw, 0, wave, lane, aw[0]);
  {
    const f16* bb = Bsrc + lane * 8;
    bn[0][0] = *(const f16x8*)bb;
    bn[0][1] = *(const f16x8*)(bb + 512);
  }
#pragma unroll
  for (int ks = 0; ks < NS; ks++) {
    if (ks + 1 < NS) {
      load_a<PACKED>(Wblk, Wraw, ks + 1, wave, lane, aw[(ks + 1) & 1]);
      const f16* bb = Bsrc + (ks + 1) * 1024 + lane * 8;
      bn[(ks + 1) & 1][0] = *(const f16x8*)bb;
      bn[(ks + 1) & 1][1] = *(const f16x8*)(bb + 512);
    }
    __builtin_amdgcn_s_setprio(1);
#pragma unroll
    for (int it = 0; it < 2; it++) {
      acc[it][0] = __builtin_amdgcn_mfma_f32_32x32x16_f16(
          aw[ks & 1][it], bn[ks & 1][0], acc[it][0], 0, 0, 0);
      acc[it][1] = __builtin_amdgcn_mfma_f32_32x32x16_f16(
          aw[ks & 1][it], bn[ks & 1][1], acc[it][1], 0, 0, 0);
    }
    __builtin_amdgcn_s_setprio(0);
  }
}

// One MLP layer, transposed: Tout = tanh(W^T(512xK) . Tin(Kx64) + b), both
// tiles in B-frag layout. Wave w owns output rows k' in [64w,64w+64).
// C/D (m74/m101): col j = jt*32+(lane&31); k' = wave*64+it*32+rr+8rq+4h,
// rr=0..3 consecutive -> f16x4 ds_write_b64 per (it,jt,rq).
// Write elem = wave*4096 + (lane&31)*8 + 4h + it*2048 + jt*512
//              + (rq>>1)*1024 + (rq&1)*256.   [verified R11]
template <int NS, bool PACKED, bool ALIASED>
__device__ __forceinline__ void mlp_layer(const f16* __restrict__ Wblk,
                                          const float* __restrict__ Wraw,
                                          const float* __restrict__ bias,
                                          const f16* Bsrc, f16* Tout,
                                          int wave, int lane) {
  f32x16 acc[2][2];
#pragma unroll
  for (int it = 0; it < 2; it++)
#pragma unroll
    for (int jt = 0; jt < 2; jt++)
#pragma unroll
      for (int e = 0; e < 16; e++) acc[it][jt][e] = 0.f;

  kloop<NS, PACKED>(Wblk, Wraw, Bsrc, wave, lane, acc);

  // Bias + tanh + f16 pack BEFORE the barrier (pure reg/VALU work).
  const int h = lane >> 5;
  f16x4 hv[2][2][4];
#pragma unroll
  for (int it = 0; it < 2; it++)
#pragma unroll
    for (int rq = 0; rq < 4; rq++) {
      float4 bv = *(const float4*)&bias[wave * 64 + it * 32 + rq * 8 + h * 4];
#pragma unroll
      for (int jt = 0; jt < 2; jt++) {
        f16x4 v;
#pragma unroll
        for (int rr = 0; rr < 4; rr++)
          v[rr] = (f16)fast_tanh(acc[it][jt][rq * 4 + rr] + (&bv.x)[rr]);
        hv[it][jt][rq] = v;
      }
    }

  if (ALIASED) __syncthreads();  // all waves done reading Bsrc (== Tout)

  f16* wb = Tout + wave * 4096 + (lane & 31) * 8 + 4 * h;
#pragma unroll
  for (int it = 0; it < 2; it++)
#pragma unroll
    for (int jt = 0; jt < 2; jt++)
#pragma unroll
      for (int rq = 0; rq < 4; rq++)
        *(f16x4*)(wb + it * 2048 + jt * 512 + (rq >> 1) * 1024 + (rq & 1) * 256) =
            hv[it][jt][rq];
  __syncthreads();
}

// L3 + fused diagonal epilogue, all in registers: after the K-loop each
// lane holds acc3 for k' = wave*64+it*32+rq*8+4h+rr, d = jt*32+(lane&31).
// ds_partial[d] += tanh(acc3 + b3[k']) * W4[k'*64 + d]; W4 read raw fp32
// (lanes 0-31 coalesce per instruction). Cross-h combine via shfl_down(32);
// lanes 0-31 write 2 floats to pp. No H3 LDS write, no epilogue LDS reads.
template <int NS, bool PACKED>
__device__ __forceinline__ void l3_diag(const f16* __restrict__ Wblk,
                                        const float* __restrict__ Wraw,
                                        const float* __restrict__ b3,
                                        const float* __restrict__ W4,
                                        const f16* Bsrc, float* pp,
                                        int wave, int lane) {
  f32x16 acc[2][2];
#pragma unroll
  for (int it = 0; it < 2; it++)
#pragma unroll
    for (int jt = 0; jt < 2; jt++)
#pragma unroll
      for (int e = 0; e < 16; e++) acc[it][jt][e] = 0.f;

  kloop<NS, PACKED>(Wblk, Wraw, Bsrc, wave, lane, acc);

  const int h = lane >> 5, dl = lane & 31;
  float p0 = 0.f, p1 = 0.f;
#pragma unroll
  for (int it = 0; it < 2; it++)
#pragma unroll
    for (int rq = 0; rq < 4; rq++) {
      float4 bv = *(const float4*)&b3[wave * 64 + it * 32 + rq * 8 + h * 4];
#pragma unroll
      for (int rr = 0; rr < 4; rr++) {
        int kp = wave * 64 + it * 32 + rq * 8 + h * 4 + rr;
        const float* wrow = W4 + kp * 64 + dl;
        float h30 = fast_tanh(acc[it][0][rq * 4 + rr] + (&bv.x)[rr]);
        float h31 = fast_tanh(acc[it][1][rq * 4 + rr] + (&bv.x)[rr]);
        p0 = fmaf(h30, wrow[0], p0);
        p1 = fmaf(h31, wrow[32], p1);
      }
    }
  p0 += __shfl_down(p0, 32);
  p1 += __shfl_down(p1, 32);
  if (lane < 32) {
    pp[wave * 64 + lane] = p0;
    pp[wave * 64 + 32 + lane] = p1;
  }
  __syncthreads();
}

template <bool PACKED>
__global__ __launch_bounds__(512, 4) void decoder_main(
    const float* __restrict__ x, const float* __restrict__ koop,
    const f16* __restrict__ wpack,
    const float* __restrict__ sW1, const float* __restrict__ sW2,
    const float* __restrict__ sW3, const float* __restrict__ sW4,
    const float* __restrict__ tW1, const float* __restrict__ tW2,
    const float* __restrict__ tW3, const float* __restrict__ tW4,
    const float* __restrict__ sb1, const float* __restrict__ sb2,
    const float* __restrict__ sb3, const float* __restrict__ sb4,
    const float* __restrict__ tb1, const float* __restrict__ tb2,
    const float* __restrict__ tb3, const float* __restrict__ tb4,
    float* __restrict__ out) {
  __shared__ __align__(16) f16 ZB[4096];   // koop tile, B-frag order (8 KB)
  __shared__ __align__(16) f16 HA[32768];  // activations T[k][j] (64 KB)
  __shared__ float pp[512];                // diag partials 8x64 (2 KB)
  __shared__ float redBuf[2][64];          // ds, dt
  // ~74.6 KB; 512 thr, ~110 regs -> 2 blocks/CU (16 waves, 4/SIMD)

  const int b = blockIdx.x;
  const int t = threadIdx.x;
  const int wave = t >> 6, lane = t & 63;

  // Stage layer-1 B-operand: B[k][j] = koop[b][k][j], raw row-major tile.
  const float* kb = koop + b * 4096;
#pragma unroll
  for (int i = 0; i < 8; i++) {
    int flat = t + 512 * i;                 // k = flat>>6, j = flat&63
    ZB[zbidx(flat >> 6, flat & 63)] = (f16)kb[flat];
  }
  __syncthreads();

  for (int net = 0; net < 2; net++) {
    const f16* wb = PACKED ? (wpack + net * WPACK_PER_NET) : (const f16*)0;
    const float* W1 = net ? tW1 : sW1;
    const float* W2 = net ? tW2 : sW2;
    const float* W3 = net ? tW3 : sW3;
    const float* W4 = net ? tW4 : sW4;
    const float* b1 = net ? tb1 : sb1;
    const float* b2 = net ? tb2 : sb2;
    const float* b3 = net ? tb3 : sb3;
    const float* b4 = net ? tb4 : sb4;
    // L1 reads ZB (never overwritten), writes HA -> no pre-write barrier.
    mlp_layer<4, PACKED, false>(PACKED ? wb + OFF_W1 : 0, W1, b1, ZB, HA, wave, lane);
    mlp_layer<32, PACKED, true>(PACKED ? wb + OFF_W2 : 0, W2, b2, HA, HA, wave, lane);
    l3_diag<32, PACKED>(PACKED ? wb + OFF_W3 : 0, W3, b3, W4, HA, pp, wave, lane);

    if (t < 64) {
      float s = b4[t];
#pragma unroll
      for (int o = 0; o < 8; o++) s += pp[o * 64 + t];
      redBuf[net][t] = s;
    }
    __syncthreads();  // pp/HA reusable; redBuf[net] visible at the end
  }

  if (t < 64) {
    out[b * 64 + t] = (x[b * 64 + t] - redBuf[1][t]) * __expf(-redBuf[0][t]);
  }
}

extern "C" void kernel_launch(void* const* d_in, const int* in_sizes, int n_in,
                              void* d_out, int out_size, void* d_ws, size_t ws_size,
                              hipStream_t stream) {
  const float* x    = (const float*)d_in[0];
  const float* koop = (const float*)d_in[1];
  const float* sW1 = (const float*)d_in[2];  const float* sb1 = (const float*)d_in[3];
  const float* sW2 = (const float*)d_in[4];  const float* sb2 = (const float*)d_in[5];
  const float* sW3 = (const float*)d_in[6];  const float* sb3 = (const float*)d_in[7];
  const float* sW4 = (const float*)d_in[8];  const float* sb4 = (const float*)d_in[9];
  const float* tW1 = (const float*)d_in[10]; const float* tb1 = (const float*)d_in[11];
  const float* tW2 = (const float*)d_in[12]; const float* tb2 = (const float*)d_in[13];
  const float* tW3 = (const float*)d_in[14]; const float* tb3 = (const float*)d_in[15];
  const float* tW4 = (const float*)d_in[16]; const float* tb4 = (const float*)d_in[17];
  float* out = (float*)d_out;

  // Launch-invariant branch (ws_size constant across calls) -> graph-safe.
  // NEVER write past ws_size (R1: OOB pack corrupted harness allocations).
  if (ws_size >= (size_t)WPACK_BYTES) {
    f16* wpack = (f16*)d_ws;
    pack_weights<<<544, 256, 0, stream>>>(sW1, sW2, sW3, tW1, tW2, tW3, wpack);
    decoder_main<true><<<2048, 512, 0, stream>>>(
        x, koop, wpack, sW1, sW2, sW3, sW4, tW1, tW2, tW3, tW4,
        sb1, sb2, sb3, sb4, tb1, tb2, tb3, tb4, out);
  } else {
    decoder_main<false><<<2048, 512, 0, stream>>>(
        x, koop, (const f16*)0, sW1, sW2, sW3, sW4, tW1, tW2, tW3, tW4,
        sb1, sb2, sb3, sb4, tb1, tb2, tb3, tb4, out);
  }
}